// Round 1
// baseline (43442.276 us; speedup 1.0000x reference)
//
#include <hip/hip_runtime.h>
#include <float.h>

// Problem constants (fixed shapes from setup_inputs)
#define NN 4096      // b*n
#define DD 640       // d
#define DE 512       // embed/inner dim
#define NB 32        // LU panel width
#define NPAN (NN/NB) // 128 panels
#define SB 128       // solve block
#define NSB (NN/SB)  // 32 solve blocks

static __device__ __forceinline__ float4 ldg4(const float* p) { return *(const float4*)p; }

// ---------------------------------------------------------------------------
// 1) q = xe@Wq, k = xe@Wk  (xe = xf[:, :512], ld 640). Fused dual GEMM.
//    64x64 tile / WG, kb=32, 4x4 micro-tile per thread (x2 outputs).
// ---------------------------------------------------------------------------
__global__ __launch_bounds__(256) void proj_gemm(
    const float* __restrict__ xf, const float* __restrict__ Wq,
    const float* __restrict__ Wk, float* __restrict__ q, float* __restrict__ kk_)
{
  __shared__ float Xs[32][68], Qs[32][68], Ks[32][68];
  const int i0 = blockIdx.x * 64, c0 = blockIdx.y * 64;
  const int t = threadIdx.x, tr = t >> 4, tc = t & 15;
  float accq[4][4] = {}, acck[4][4] = {};
  for (int kb = 0; kb < DE; kb += 32) {
    {
      int m = t >> 3, k4 = (t & 7) << 2;
      float4 v0 = ldg4(xf + (size_t)(i0 + m) * DD + kb + k4);
      float4 v1 = ldg4(xf + (size_t)(i0 + m + 32) * DD + kb + k4);
      Xs[k4+0][m] = v0.x; Xs[k4+1][m] = v0.y; Xs[k4+2][m] = v0.z; Xs[k4+3][m] = v0.w;
      Xs[k4+0][m+32] = v1.x; Xs[k4+1][m+32] = v1.y; Xs[k4+2][m+32] = v1.z; Xs[k4+3][m+32] = v1.w;
    }
    {
      int kr = t >> 3, n8 = (t & 7) << 3;
      *(float4*)&Qs[kr][n8]   = ldg4(Wq + (size_t)(kb + kr) * DE + c0 + n8);
      *(float4*)&Qs[kr][n8+4] = ldg4(Wq + (size_t)(kb + kr) * DE + c0 + n8 + 4);
      *(float4*)&Ks[kr][n8]   = ldg4(Wk + (size_t)(kb + kr) * DE + c0 + n8);
      *(float4*)&Ks[kr][n8+4] = ldg4(Wk + (size_t)(kb + kr) * DE + c0 + n8 + 4);
    }
    __syncthreads();
    #pragma unroll
    for (int kkk = 0; kkk < 32; ++kkk) {
      float a[4], bq[4], bk[4];
      *(float4*)a  = *(const float4*)&Xs[kkk][tr << 2];
      *(float4*)bq = *(const float4*)&Qs[kkk][tc << 2];
      *(float4*)bk = *(const float4*)&Ks[kkk][tc << 2];
      #pragma unroll
      for (int r = 0; r < 4; ++r)
        #pragma unroll
        for (int c = 0; c < 4; ++c) { accq[r][c] += a[r]*bq[c]; acck[r][c] += a[r]*bk[c]; }
    }
    __syncthreads();
  }
  #pragma unroll
  for (int r = 0; r < 4; ++r) {
    float* qp = q   + (size_t)(i0 + (tr<<2) + r) * DE + c0 + (tc<<2);
    float* kp = kk_ + (size_t)(i0 + (tr<<2) + r) * DE + c0 + (tc<<2);
    *(float4*)qp = make_float4(accq[r][0], accq[r][1], accq[r][2], accq[r][3]);
    *(float4*)kp = make_float4(acck[r][0], acck[r][1], acck[r][2], acck[r][3]);
  }
}

// ---------------------------------------------------------------------------
// 2) row squared norms: q2[i]=sum q[i,:]^2, k2[i]=sum k[i,:]^2. wave per row.
// ---------------------------------------------------------------------------
__global__ __launch_bounds__(256) void rownorm(
    const float* __restrict__ q, const float* __restrict__ kk_,
    float* __restrict__ q2, float* __restrict__ k2)
{
  int w = (blockIdx.x * 256 + threadIdx.x) >> 6;   // global wave id, 0..2*NN-1
  int lane = threadIdx.x & 63;
  const float* src = (w < NN) ? q : kk_;
  int row = (w < NN) ? w : w - NN;
  const float* p = src + (size_t)row * DE;
  float s = 0.f;
  for (int c = lane; c < DE; c += 64) { float v = p[c]; s += v * v; }
  for (int off = 32; off; off >>= 1) s += __shfl_down(s, off);
  if (lane == 0) { if (w < NN) q2[row] = s; else k2[row] = s; }
}

// ---------------------------------------------------------------------------
// 3) dots = (q2[i]+k2[j]-2*q@k^T)/DE  (A * B^T GEMM, 64x64 tile)
// ---------------------------------------------------------------------------
__global__ __launch_bounds__(256) void dots_gemm(
    const float* __restrict__ q, const float* __restrict__ kk_,
    const float* __restrict__ q2, const float* __restrict__ k2,
    float* __restrict__ dots)
{
  __shared__ float Qs[32][68], Ks[32][68];
  const int i0 = blockIdx.x * 64, j0 = blockIdx.y * 64;
  const int t = threadIdx.x, tr = t >> 4, tc = t & 15;
  float acc[4][4] = {};
  for (int kb = 0; kb < DE; kb += 32) {
    int m = t >> 3, k4 = (t & 7) << 2;
    {
      float4 v0 = ldg4(q + (size_t)(i0 + m) * DE + kb + k4);
      float4 v1 = ldg4(q + (size_t)(i0 + m + 32) * DE + kb + k4);
      Qs[k4+0][m] = v0.x; Qs[k4+1][m] = v0.y; Qs[k4+2][m] = v0.z; Qs[k4+3][m] = v0.w;
      Qs[k4+0][m+32] = v1.x; Qs[k4+1][m+32] = v1.y; Qs[k4+2][m+32] = v1.z; Qs[k4+3][m+32] = v1.w;
    }
    {
      float4 v0 = ldg4(kk_ + (size_t)(j0 + m) * DE + kb + k4);
      float4 v1 = ldg4(kk_ + (size_t)(j0 + m + 32) * DE + kb + k4);
      Ks[k4+0][m] = v0.x; Ks[k4+1][m] = v0.y; Ks[k4+2][m] = v0.z; Ks[k4+3][m] = v0.w;
      Ks[k4+0][m+32] = v1.x; Ks[k4+1][m+32] = v1.y; Ks[k4+2][m+32] = v1.z; Ks[k4+3][m+32] = v1.w;
    }
    __syncthreads();
    #pragma unroll
    for (int kkk = 0; kkk < 32; ++kkk) {
      float a[4], b[4];
      *(float4*)a = *(const float4*)&Qs[kkk][tr << 2];
      *(float4*)b = *(const float4*)&Ks[kkk][tc << 2];
      #pragma unroll
      for (int r = 0; r < 4; ++r)
        #pragma unroll
        for (int c = 0; c < 4; ++c) acc[r][c] += a[r]*b[c];
    }
    __syncthreads();
  }
  const float inv = 1.0f / (float)DE;
  float k2v[4]; *(float4*)k2v = ldg4(k2 + j0 + (tc<<2));
  #pragma unroll
  for (int r = 0; r < 4; ++r) {
    float q2v = q2[i0 + (tr<<2) + r];
    float o[4];
    #pragma unroll
    for (int c = 0; c < 4; ++c) o[c] = (q2v + k2v[c] - 2.0f*acc[r][c]) * inv;
    *(float4*)(dots + (size_t)(i0 + (tr<<2) + r) * NN + j0 + (tc<<2)) =
        make_float4(o[0], o[1], o[2], o[3]);
  }
}

// ---------------------------------------------------------------------------
// 4) per-row top-64 (largest) -> bit mask rows. One WG (256 thr) per row.
//    Iterative argmax on an LDS copy; tie -> lowest index (matches lax.top_k).
// ---------------------------------------------------------------------------
__global__ __launch_bounds__(256) void topk_bits(
    const float* __restrict__ dots, unsigned int* __restrict__ bits)
{
  __shared__ float row[NN];
  __shared__ unsigned int b[128];
  __shared__ float rv[4]; __shared__ int ri[4];
  const int i = blockIdx.x, t = threadIdx.x;
  const float* dr = dots + (size_t)i * NN;
  for (int c = t; c < NN; c += 256) row[c] = dr[c];
  if (t < 128) b[t] = 0u;
  __syncthreads();
  for (int it = 0; it < 64; ++it) {
    float bv = -FLT_MAX; int bi = NN;
    for (int c = t; c < NN; c += 256) { float v = row[c]; if (v > bv) { bv = v; bi = c; } }
    for (int off = 32; off; off >>= 1) {
      float ov = __shfl_down(bv, off); int oi = __shfl_down(bi, off);
      if (ov > bv || (ov == bv && oi < bi)) { bv = ov; bi = oi; }
    }
    if ((t & 63) == 0) { rv[t >> 6] = bv; ri[t >> 6] = bi; }
    __syncthreads();
    if (t == 0) {
      float fv = rv[0]; int fi = ri[0];
      for (int w = 1; w < 4; ++w)
        if (rv[w] > fv || (rv[w] == fv && ri[w] < fi)) { fv = rv[w]; fi = ri[w]; }
      b[fi >> 5] |= 1u << (fi & 31);
      row[fi] = -FLT_MAX;
    }
    __syncthreads();
  }
  if (t < 128) bits[(size_t)i * 128 + t] = b[t];
}

// ---------------------------------------------------------------------------
// 5) A = I - alpha * dots * (bit(i,j)|bit(j,i)), in place over dots. (EPS ~1e-16
//    is a rank-1 perturbation of norm ~1e-12 -> negligible vs 3.0 threshold.)
// ---------------------------------------------------------------------------
__global__ __launch_bounds__(256) void build_A(
    float* __restrict__ A, const unsigned int* __restrict__ bits,
    const float* __restrict__ alpha_p)
{
  int tid = blockIdx.x * 256 + threadIdx.x;           // over NN*NN/4
  int i = tid >> 10;
  int j4 = (tid & 1023) << 2;
  float alpha = alpha_p[0];
  float* p = A + (size_t)i * NN + j4;
  float4 d = *(float4*)p;
  unsigned int wrow = bits[(size_t)i * 128 + (j4 >> 5)];
  float dv[4] = {d.x, d.y, d.z, d.w}, o[4];
  #pragma unroll
  for (int u = 0; u < 4; ++u) {
    int j = j4 + u;
    unsigned int m1 = (wrow >> (j & 31)) & 1u;
    unsigned int m2 = (bits[(size_t)j * 128 + (i >> 5)] >> (i & 31)) & 1u;
    float base = (i == j) ? 1.0f : 0.0f;
    o[u] = base - ((m1 | m2) ? alpha * dv[u] : 0.0f);
  }
  *(float4*)p = make_float4(o[0], o[1], o[2], o[3]);
}

// ---------------------------------------------------------------------------
// 6) LU panel (32 cols), partial pivoting. One WG, 1024 threads; panel rows in
//    registers (a[4][32], fully unrolled -> static indices). Emits ipiv and
//    the net row-permutation pairs for the laswp gather.
// ---------------------------------------------------------------------------
__global__ __launch_bounds__(1024) void lu_panel(
    float* __restrict__ A, int k0, int* __restrict__ piv,
    int* __restrict__ pr_dst, int* __restrict__ pr_src)
{
  const int t = threadIdx.x;
  const int M = NN - k0;
  float a[4][NB];
  __shared__ float bufA[NB], bufB[NB];
  __shared__ float rv[16]; __shared__ int ri[16];
  __shared__ int s_pr;
  __shared__ int piv_s[NB];

  #pragma unroll
  for (int i = 0; i < 4; ++i) {
    int r = t + (i << 10);
    if (r < M) {
      const float* src = A + (size_t)(k0 + r) * NN + k0;
      #pragma unroll
      for (int c4 = 0; c4 < NB; c4 += 4) {
        float4 v = ldg4(src + c4);
        a[i][c4] = v.x; a[i][c4+1] = v.y; a[i][c4+2] = v.z; a[i][c4+3] = v.w;
      }
    }
  }

  #pragma unroll
  for (int j = 0; j < NB; ++j) {
    // --- pivot search over rows r >= j ---
    float bv = -1.0f; int br = 1 << 30;
    #pragma unroll
    for (int i = 0; i < 4; ++i) {
      int r = t + (i << 10);
      if (r >= j && r < M) {
        float v = fabsf(a[i][j]);
        if (v > bv || (v == bv && r < br)) { bv = v; br = r; }
      }
    }
    for (int off = 32; off; off >>= 1) {
      float ov = __shfl_down(bv, off); int orr = __shfl_down(br, off);
      if (ov > bv || (ov == bv && orr < br)) { bv = ov; br = orr; }
    }
    if ((t & 63) == 0) { rv[t >> 6] = bv; ri[t >> 6] = br; }
    __syncthreads();
    if (t == 0) {
      float fv = rv[0]; int fr = ri[0];
      for (int w = 1; w < 16; ++w)
        if (rv[w] > fv || (rv[w] == fv && ri[w] < fr)) { fv = rv[w]; fr = ri[w]; }
      s_pr = fr; piv_s[j] = k0 + fr;
    }
    __syncthreads();
    const int pr = s_pr, prT = pr & 1023, prS = pr >> 10;
    // --- swap rows j <-> pr via LDS (panel cols only) ---
    if (t == prT) {
      #pragma unroll
      for (int i2 = 0; i2 < 4; ++i2) if (i2 == prS) {
        #pragma unroll
        for (int c = 0; c < NB; ++c) bufB[c] = a[i2][c];
      }
    }
    if (t == j) {
      #pragma unroll
      for (int c = 0; c < NB; ++c) bufA[c] = a[0][c];
    }
    __syncthreads();
    if (t == j) {
      #pragma unroll
      for (int c = 0; c < NB; ++c) a[0][c] = bufB[c];
    }
    if (t == prT) {
      #pragma unroll
      for (int i2 = 0; i2 < 4; ++i2) if (i2 == prS) {
        #pragma unroll
        for (int c = 0; c < NB; ++c) a[i2][c] = bufA[c];
      }
    }
    // --- scale + rank-1 update (bufB holds the post-swap pivot row) ---
    float rp = 1.0f / bufB[j];
    #pragma unroll
    for (int i = 0; i < 4; ++i) {
      int r = t + (i << 10);
      if (r > j && r < M) {
        float mlt = a[i][j] * rp;
        a[i][j] = mlt;
        #pragma unroll
        for (int c = j + 1; c < NB; ++c) a[i][c] -= mlt * bufB[c];
      }
    }
    __syncthreads();
  }

  // writeback
  #pragma unroll
  for (int i = 0; i < 4; ++i) {
    int r = t + (i << 10);
    if (r < M) {
      float* dst = A + (size_t)(k0 + r) * NN + k0;
      #pragma unroll
      for (int c4 = 0; c4 < NB; c4 += 4)
        *(float4*)(dst + c4) = make_float4(a[i][c4], a[i][c4+1], a[i][c4+2], a[i][c4+3]);
    }
  }
  if (t < NB) piv[k0 + t] = piv_s[t];

  // --- net-permutation simulation on wave 0 (<=64 touched rows) ---
  if (t < 64) {
    int slotrow = (t < NB) ? (k0 + t) : -1;
    int content = slotrow;
    int next_ext = NB;
    for (int j = 0; j < NB; ++j) {
      int p = piv_s[j];
      unsigned long long mask = __ballot(slotrow == p);
      int bslot;
      if (mask) bslot = __ffsll((unsigned long long)mask) - 1;
      else {
        bslot = next_ext;
        if (t == next_ext) { slotrow = p; content = p; }
        next_ext++;
      }
      int srcl = (t == j) ? bslot : ((t == bslot) ? j : t);
      content = __shfl(content, srcl);
    }
    pr_dst[t] = slotrow;   // -1 for unused slots
    pr_src[t] = content;
  }
}

// ---------------------------------------------------------------------------
// 7) apply the panel's net row permutation to all columns outside the panel.
//    All loads before all stores (pipelined) -> no serial swap chain.
// ---------------------------------------------------------------------------
__global__ __launch_bounds__(256) void laswp_pairs(
    float* __restrict__ A, int k0,
    const int* __restrict__ pr_dst, const int* __restrict__ pr_src)
{
  __shared__ int sd[64], ss[64];
  int t = threadIdx.x;
  if (t < 64) { sd[t] = pr_dst[t]; ss[t] = pr_src[t]; }
  __syncthreads();
  int cg = blockIdx.x * 256 + t;
  if (cg >= NN - NB) return;
  int c = (cg < k0) ? cg : cg + NB;
  float tmp[64];
  #pragma unroll
  for (int i = 0; i < 64; ++i)
    tmp[i] = (sd[i] >= 0 && sd[i] != ss[i]) ? A[(size_t)ss[i] * NN + c] : 0.0f;
  #pragma unroll
  for (int i = 0; i < 64; ++i)
    if (sd[i] >= 0 && sd[i] != ss[i]) A[(size_t)sd[i] * NN + c] = tmp[i];
}

// ---------------------------------------------------------------------------
// 8) TRSM: U12 = L11^{-1} * A12 (unit lower 32x32), one column per thread.
// ---------------------------------------------------------------------------
__global__ __launch_bounds__(256) void trsm32(float* __restrict__ A, int k0)
{
  __shared__ float l[32][33];
  int t = threadIdx.x;
  {
    int i = t >> 3, j4 = (t & 7) << 2;
    float4 v = ldg4(A + (size_t)(k0 + i) * NN + k0 + j4);
    l[i][j4] = v.x; l[i][j4+1] = v.y; l[i][j4+2] = v.z; l[i][j4+3] = v.w;
  }
  __syncthreads();
  int c = k0 + NB + blockIdx.x * 256 + t;
  if (c >= NN) return;
  float x[32];
  #pragma unroll
  for (int i = 0; i < 32; ++i) x[i] = A[(size_t)(k0 + i) * NN + c];
  #pragma unroll
  for (int i = 1; i < 32; ++i)
    #pragma unroll
    for (int j = 0; j < i; ++j) x[i] -= l[i][j] * x[j];
  #pragma unroll
  for (int i = 0; i < 32; ++i) A[(size_t)(k0 + i) * NN + c] = x[i];
}

// ---------------------------------------------------------------------------
// 9) generic in-place C -= Aop * Bop  (M x Nc, K multiple of 32). 64x64 tile.
//    Used for LU trailing updates (K=32) and solve rank-128 updates.
// ---------------------------------------------------------------------------
__global__ __launch_bounds__(256) void rank_update(
    float* __restrict__ C, int ldc,
    const float* __restrict__ Aop, int lda,
    const float* __restrict__ Bop, int ldb,
    int Mr, int Nc, int K)
{
  __shared__ float As[32][68], Bs[32][68];
  const int m0 = blockIdx.x * 64, n0 = blockIdx.y * 64;
  const int t = threadIdx.x, tr = t >> 4, tc = t & 15;
  const float4 z4 = make_float4(0.f, 0.f, 0.f, 0.f);
  float acc[4][4] = {};
  for (int kb = 0; kb < K; kb += 32) {
    {
      int m = t >> 3, k4 = (t & 7) << 2;
      float4 v0 = (m0 + m < Mr) ? ldg4(Aop + (size_t)(m0 + m) * lda + kb + k4) : z4;
      float4 v1 = (m0 + m + 32 < Mr) ? ldg4(Aop + (size_t)(m0 + m + 32) * lda + kb + k4) : z4;
      As[k4+0][m] = v0.x; As[k4+1][m] = v0.y; As[k4+2][m] = v0.z; As[k4+3][m] = v0.w;
      As[k4+0][m+32] = v1.x; As[k4+1][m+32] = v1.y; As[k4+2][m+32] = v1.z; As[k4+3][m+32] = v1.w;
    }
    {
      int kr = t >> 3, n8 = (t & 7) << 3;
      bool ok = (n0 + n8 < Nc);
      float4 w0 = ok ? ldg4(Bop + (size_t)(kb + kr) * ldb + n0 + n8) : z4;
      float4 w1 = ok ? ldg4(Bop + (size_t)(kb + kr) * ldb + n0 + n8 + 4) : z4;
      *(float4*)&Bs[kr][n8] = w0; *(float4*)&Bs[kr][n8+4] = w1;
    }
    __syncthreads();
    #pragma unroll
    for (int kkk = 0; kkk < 32; ++kkk) {
      float a[4], b[4];
      *(float4*)a = *(const float4*)&As[kkk][tr << 2];
      *(float4*)b = *(const float4*)&Bs[kkk][tc << 2];
      #pragma unroll
      for (int r = 0; r < 4; ++r)
        #pragma unroll
        for (int c = 0; c < 4; ++c) acc[r][c] += a[r] * b[c];
    }
    __syncthreads();
  }
  #pragma unroll
  for (int r = 0; r < 4; ++r) {
    int m = m0 + (tr << 2) + r;
    int n = n0 + (tc << 2);
    if (m < Mr && n < Nc) {
      float* cp = C + (size_t)m * ldc + n;
      float4 cv = *(float4*)cp;
      cv.x -= acc[r][0]; cv.y -= acc[r][1]; cv.z -= acc[r][2]; cv.w -= acc[r][3];
      *(float4*)cp = cv;
    }
  }
}

// ---------------------------------------------------------------------------
// 10) invert the 32 diagonal 128x128 blocks of L (unit lower) / U (upper).
//     One WG (128 threads) per block; one inverse column per thread; T read
//     from global (uniform -> scalar loads); xs in LDS (exactly 64KB).
// ---------------------------------------------------------------------------
__global__ __launch_bounds__(128) void inv_tri(
    const float* __restrict__ Ag, float* __restrict__ invT, int upper)
{
  __shared__ float xs[128][128];
  const int s = blockIdx.x, t = threadIdx.x;
  const size_t r0 = (size_t)s * SB;
  for (int i = 0; i < 128; ++i) xs[i][t] = 0.0f;
  const float* Tb = Ag + r0 * NN + r0;   // block base, ld NN
  if (!upper) {
    xs[t][t] = 1.0f;
    for (int i = 1; i < 128; ++i) {
      float ssum = 0.f;
      for (int j = 0; j < i; ++j) ssum += Tb[(size_t)i * NN + j] * xs[j][t];
      if (i != t) xs[i][t] = -ssum;
    }
  } else {
    xs[t][t] = 1.0f / Tb[(size_t)t * NN + t];
    for (int i = 126; i >= 0; --i) {
      float ssum = 0.f;
      for (int j = i + 1; j < 128; ++j) ssum += Tb[(size_t)i * NN + j] * xs[j][t];
      if (i != t) xs[i][t] = -ssum / Tb[(size_t)i * NN + i];
    }
  }
  for (int i = 0; i < 128; ++i) invT[(size_t)s * SB * SB + (size_t)i * SB + t] = xs[i][t];
}

// ---------------------------------------------------------------------------
// 11) compose the pivot swap sequence into a gather permutation idxp:
//     final position r holds original row idxp[r]. Backward trace, uniform j.
// ---------------------------------------------------------------------------
__global__ __launch_bounds__(1024) void perm_compose(
    const int* __restrict__ piv, int* __restrict__ idxp)
{
  __shared__ int pl[NN];
  const int t = threadIdx.x;
  for (int j = t; j < NN; j += 1024) pl[j] = piv[j];
  __syncthreads();
  int pos[4] = { t, t + 1024, t + 2048, t + 3072 };
  for (int j = NN - 1; j >= 0; --j) {
    int p = pl[j];
    #pragma unroll
    for (int u = 0; u < 4; ++u) {
      int r = t + (u << 10);
      if (j <= r) {
        if (pos[u] == j) pos[u] = p;
        else if (pos[u] == p) pos[u] = j;
      }
    }
  }
  #pragma unroll
  for (int u = 0; u < 4; ++u) idxp[t + (u << 10)] = pos[u];
}

// 12) out[r][:] = xf[idxp[r]][:]  (apply P to the RHS)
__global__ __launch_bounds__(256) void gather_rows(
    const float* __restrict__ xf, const int* __restrict__ idxp, float* __restrict__ out)
{
  const int r = blockIdx.x, t = threadIdx.x;
  const int src = idxp[r];
  const float4* s = (const float4*)(xf + (size_t)src * DD);
  float4* d = (float4*)(out + (size_t)r * DD);
  for (int c = t; c < DD / 4; c += 256) d[c] = s[c];
}

// ---------------------------------------------------------------------------
// 13) in-place diag block apply: B[r0:r0+128, :] = Minv(128x128) @ same.
//     Each WG owns a 64-col stripe: stage it in LDS, sync, then overwrite.
// ---------------------------------------------------------------------------
__global__ __launch_bounds__(256) void diag_apply(
    float* __restrict__ B, const float* __restrict__ Minv, int r0)
{
  __shared__ float Bs[128][68];
  const int c0 = blockIdx.x * 64, t = threadIdx.x;
  #pragma unroll
  for (int v = 0; v < 8; ++v) {
    int id = t + v * 256;
    int k = id >> 4, c4 = (id & 15) << 2;
    *(float4*)&Bs[k][c4] = ldg4(B + (size_t)(r0 + k) * DD + c0 + c4);
  }
  __syncthreads();
  const int tr = t >> 4, tc = t & 15;   // rows tr*8..+8, cols tc*4..+4
  float acc[8][4] = {};
  for (int k4 = 0; k4 < 128; k4 += 4) {
    float b0[4], b1[4], b2[4], b3[4];
    *(float4*)b0 = *(const float4*)&Bs[k4+0][tc << 2];
    *(float4*)b1 = *(const float4*)&Bs[k4+1][tc << 2];
    *(float4*)b2 = *(const float4*)&Bs[k4+2][tc << 2];
    *(float4*)b3 = *(const float4*)&Bs[k4+3][tc << 2];
    #pragma unroll
    for (int rr = 0; rr < 8; ++rr) {
      float m[4]; *(float4*)m = ldg4(Minv + (size_t)(tr*8 + rr) * SB + k4);
      #pragma unroll
      for (int c = 0; c < 4; ++c)
        acc[rr][c] += m[0]*b0[c] + m[1]*b1[c] + m[2]*b2[c] + m[3]*b3[c];
    }
  }
  #pragma unroll
  for (int rr = 0; rr < 8; ++rr)
    *(float4*)(B + (size_t)(r0 + tr*8 + rr) * DD + c0 + (tc << 2)) =
        make_float4(acc[rr][0], acc[rr][1], acc[rr][2], acc[rr][3]);
}

// ---------------------------------------------------------------------------
extern "C" void kernel_launch(void* const* d_in, const int* in_sizes, int n_in,
                              void* d_out, int out_size, void* d_ws, size_t ws_size,
                              hipStream_t stream)
{
  const float* xf    = (const float*)d_in[0];
  const float* Wq    = (const float*)d_in[1];
  const float* Wk    = (const float*)d_in[2];
  const float* alpha = (const float*)d_in[3];
  float* out = (float*)d_out;
  char* ws = (char*)d_ws;

  // workspace layout (~86.2 MB)
  float* Amat = (float*)(ws);                          // 64 MB  (dots -> A -> LU)
  float* q    = (float*)(ws + 67108864ull);            // 8 MB
  float* kbuf = (float*)(ws + 75497472ull);            // 8 MB
  float* invL = (float*)(ws + 83886080ull);            // 2 MB
  float* invU = (float*)(ws + 85983232ull);            // 2 MB
  unsigned int* bits = (unsigned int*)(ws + 88080384ull); // 2 MB
  float* q2   = (float*)(ws + 90177536ull);
  float* k2   = (float*)(ws + 90193920ull);
  int* piv    = (int*)(ws + 90210304ull);
  int* idxp   = (int*)(ws + 90226688ull);
  int* prd    = (int*)(ws + 90243072ull);              // 128 panels x 64
  int* prs    = (int*)(ws + 90275840ull);

  proj_gemm<<<dim3(NN/64, DE/64), 256, 0, stream>>>(xf, Wq, Wk, q, kbuf);
  rownorm<<<2 * NN / 4, 256, 0, stream>>>(q, kbuf, q2, k2);
  dots_gemm<<<dim3(NN/64, NN/64), 256, 0, stream>>>(q, kbuf, q2, k2, Amat);
  topk_bits<<<NN, 256, 0, stream>>>(Amat, bits);
  build_A<<<NN * NN / 4 / 256, 256, 0, stream>>>(Amat, bits, alpha);

  // LU with partial pivoting, NB=32 panels
  for (int p = 0; p < NPAN; ++p) {
    int k0 = p * NB;
    lu_panel<<<1, 1024, 0, stream>>>(Amat, k0, piv, prd + p * 64, prs + p * 64);
    laswp_pairs<<<(NN - NB + 255) / 256, 256, 0, stream>>>(Amat, k0, prd + p * 64, prs + p * 64);
    if (k0 + NB < NN) {
      int M2 = NN - k0 - NB;
      trsm32<<<(M2 + 255) / 256, 256, 0, stream>>>(Amat, k0);
      rank_update<<<dim3((M2 + 63) / 64, (M2 + 63) / 64), 256, 0, stream>>>(
          Amat + (size_t)(k0 + NB) * NN + (k0 + NB), NN,
          Amat + (size_t)(k0 + NB) * NN + k0, NN,
          Amat + (size_t)k0 * NN + (k0 + NB), NN,
          M2, M2, NB);
    }
  }

  inv_tri<<<NSB, 128, 0, stream>>>(Amat, invL, 0);
  inv_tri<<<NSB, 128, 0, stream>>>(Amat, invU, 1);
  perm_compose<<<1, 1024, 0, stream>>>(piv, idxp);
  gather_rows<<<NN, 256, 0, stream>>>(xf, idxp, out);

  // forward solve L y = P b  (right-looking, block 128)
  for (int s = 0; s < NSB; ++s) {
    int r0 = s * SB;
    diag_apply<<<DD / 64, 256, 0, stream>>>(out, invL + (size_t)s * SB * SB, r0);
    if (r0 + SB < NN) {
      int M2 = NN - r0 - SB;
      rank_update<<<dim3(M2 / 64, DD / 64), 256, 0, stream>>>(
          out + (size_t)(r0 + SB) * DD, DD,
          Amat + (size_t)(r0 + SB) * NN + r0, NN,
          out + (size_t)r0 * DD, DD,
          M2, DD, SB);
    }
  }
  // backward solve U x = y
  for (int s = NSB - 1; s >= 0; --s) {
    int r0 = s * SB;
    diag_apply<<<DD / 64, 256, 0, stream>>>(out, invU + (size_t)s * SB * SB, r0);
    if (r0 > 0) {
      rank_update<<<dim3(r0 / 64, DD / 64), 256, 0, stream>>>(
          out, DD,
          Amat + r0, NN,
          out + (size_t)r0 * DD, DD,
          r0, DD, SB);
    }
  }
}

// Round 2
// 37817.062 us; speedup vs baseline: 1.1487x; 1.1487x over previous
//
#include <hip/hip_runtime.h>
#include <float.h>

// Problem constants (fixed shapes from setup_inputs)
#define NN 4096      // b*n
#define DD 640       // d
#define DE 512       // embed/inner dim
#define NB 16        // LU panel width (16 -> a[4][16]=64 VGPR, no spill at 1024 thr)
#define NPAN (NN/NB) // 256 panels
#define SB 128       // solve block
#define NSB (NN/SB)  // 32 solve blocks

static __device__ __forceinline__ float4 ldg4(const float* p) { return *(const float4*)p; }

// ---------------------------------------------------------------------------
// 1) q = xe@Wq, k = xe@Wk  (xe = xf[:, :512], ld 640). Fused dual GEMM.
// ---------------------------------------------------------------------------
__global__ __launch_bounds__(256) void proj_gemm(
    const float* __restrict__ xf, const float* __restrict__ Wq,
    const float* __restrict__ Wk, float* __restrict__ q, float* __restrict__ kk_)
{
  __shared__ float Xs[32][68], Qs[32][68], Ks[32][68];
  const int i0 = blockIdx.x * 64, c0 = blockIdx.y * 64;
  const int t = threadIdx.x, tr = t >> 4, tc = t & 15;
  float accq[4][4] = {}, acck[4][4] = {};
  for (int kb = 0; kb < DE; kb += 32) {
    {
      int m = t >> 3, k4 = (t & 7) << 2;
      float4 v0 = ldg4(xf + (size_t)(i0 + m) * DD + kb + k4);
      float4 v1 = ldg4(xf + (size_t)(i0 + m + 32) * DD + kb + k4);
      Xs[k4+0][m] = v0.x; Xs[k4+1][m] = v0.y; Xs[k4+2][m] = v0.z; Xs[k4+3][m] = v0.w;
      Xs[k4+0][m+32] = v1.x; Xs[k4+1][m+32] = v1.y; Xs[k4+2][m+32] = v1.z; Xs[k4+3][m+32] = v1.w;
    }
    {
      int kr = t >> 3, n8 = (t & 7) << 3;
      *(float4*)&Qs[kr][n8]   = ldg4(Wq + (size_t)(kb + kr) * DE + c0 + n8);
      *(float4*)&Qs[kr][n8+4] = ldg4(Wq + (size_t)(kb + kr) * DE + c0 + n8 + 4);
      *(float4*)&Ks[kr][n8]   = ldg4(Wk + (size_t)(kb + kr) * DE + c0 + n8);
      *(float4*)&Ks[kr][n8+4] = ldg4(Wk + (size_t)(kb + kr) * DE + c0 + n8 + 4);
    }
    __syncthreads();
    #pragma unroll
    for (int kkk = 0; kkk < 32; ++kkk) {
      float a[4], bq[4], bk[4];
      *(float4*)a  = *(const float4*)&Xs[kkk][tr << 2];
      *(float4*)bq = *(const float4*)&Qs[kkk][tc << 2];
      *(float4*)bk = *(const float4*)&Ks[kkk][tc << 2];
      #pragma unroll
      for (int r = 0; r < 4; ++r)
        #pragma unroll
        for (int c = 0; c < 4; ++c) { accq[r][c] += a[r]*bq[c]; acck[r][c] += a[r]*bk[c]; }
    }
    __syncthreads();
  }
  #pragma unroll
  for (int r = 0; r < 4; ++r) {
    float* qp = q   + (size_t)(i0 + (tr<<2) + r) * DE + c0 + (tc<<2);
    float* kp = kk_ + (size_t)(i0 + (tr<<2) + r) * DE + c0 + (tc<<2);
    *(float4*)qp = make_float4(accq[r][0], accq[r][1], accq[r][2], accq[r][3]);
    *(float4*)kp = make_float4(acck[r][0], acck[r][1], acck[r][2], acck[r][3]);
  }
}

// ---------------------------------------------------------------------------
// 2) row squared norms
// ---------------------------------------------------------------------------
__global__ __launch_bounds__(256) void rownorm(
    const float* __restrict__ q, const float* __restrict__ kk_,
    float* __restrict__ q2, float* __restrict__ k2)
{
  int w = (blockIdx.x * 256 + threadIdx.x) >> 6;
  int lane = threadIdx.x & 63;
  const float* src = (w < NN) ? q : kk_;
  int row = (w < NN) ? w : w - NN;
  const float* p = src + (size_t)row * DE;
  float s = 0.f;
  for (int c = lane; c < DE; c += 64) { float v = p[c]; s += v * v; }
  for (int off = 32; off; off >>= 1) s += __shfl_down(s, off);
  if (lane == 0) { if (w < NN) q2[row] = s; else k2[row] = s; }
}

// ---------------------------------------------------------------------------
// 3) dots = (q2[i]+k2[j]-2*q@k^T)/DE
// ---------------------------------------------------------------------------
__global__ __launch_bounds__(256) void dots_gemm(
    const float* __restrict__ q, const float* __restrict__ kk_,
    const float* __restrict__ q2, const float* __restrict__ k2,
    float* __restrict__ dots)
{
  __shared__ float Qs[32][68], Ks[32][68];
  const int i0 = blockIdx.x * 64, j0 = blockIdx.y * 64;
  const int t = threadIdx.x, tr = t >> 4, tc = t & 15;
  float acc[4][4] = {};
  for (int kb = 0; kb < DE; kb += 32) {
    int m = t >> 3, k4 = (t & 7) << 2;
    {
      float4 v0 = ldg4(q + (size_t)(i0 + m) * DE + kb + k4);
      float4 v1 = ldg4(q + (size_t)(i0 + m + 32) * DE + kb + k4);
      Qs[k4+0][m] = v0.x; Qs[k4+1][m] = v0.y; Qs[k4+2][m] = v0.z; Qs[k4+3][m] = v0.w;
      Qs[k4+0][m+32] = v1.x; Qs[k4+1][m+32] = v1.y; Qs[k4+2][m+32] = v1.z; Qs[k4+3][m+32] = v1.w;
    }
    {
      float4 v0 = ldg4(kk_ + (size_t)(j0 + m) * DE + kb + k4);
      float4 v1 = ldg4(kk_ + (size_t)(j0 + m + 32) * DE + kb + k4);
      Ks[k4+0][m] = v0.x; Ks[k4+1][m] = v0.y; Ks[k4+2][m] = v0.z; Ks[k4+3][m] = v0.w;
      Ks[k4+0][m+32] = v1.x; Ks[k4+1][m+32] = v1.y; Ks[k4+2][m+32] = v1.z; Ks[k4+3][m+32] = v1.w;
    }
    __syncthreads();
    #pragma unroll
    for (int kkk = 0; kkk < 32; ++kkk) {
      float a[4], b[4];
      *(float4*)a = *(const float4*)&Qs[kkk][tr << 2];
      *(float4*)b = *(const float4*)&Ks[kkk][tc << 2];
      #pragma unroll
      for (int r = 0; r < 4; ++r)
        #pragma unroll
        for (int c = 0; c < 4; ++c) acc[r][c] += a[r]*b[c];
    }
    __syncthreads();
  }
  const float inv = 1.0f / (float)DE;
  float k2v[4]; *(float4*)k2v = ldg4(k2 + j0 + (tc<<2));
  #pragma unroll
  for (int r = 0; r < 4; ++r) {
    float q2v = q2[i0 + (tr<<2) + r];
    float o[4];
    #pragma unroll
    for (int c = 0; c < 4; ++c) o[c] = (q2v + k2v[c] - 2.0f*acc[r][c]) * inv;
    *(float4*)(dots + (size_t)(i0 + (tr<<2) + r) * NN + j0 + (tc<<2)) =
        make_float4(o[0], o[1], o[2], o[3]);
  }
}

// ---------------------------------------------------------------------------
// 4) per-row top-64 -> bit mask rows
// ---------------------------------------------------------------------------
__global__ __launch_bounds__(256) void topk_bits(
    const float* __restrict__ dots, unsigned int* __restrict__ bits)
{
  __shared__ float row[NN];
  __shared__ unsigned int b[128];
  __shared__ float rv[4]; __shared__ int ri[4];
  const int i = blockIdx.x, t = threadIdx.x;
  const float* dr = dots + (size_t)i * NN;
  for (int c = t; c < NN; c += 256) row[c] = dr[c];
  if (t < 128) b[t] = 0u;
  __syncthreads();
  for (int it = 0; it < 64; ++it) {
    float bv = -FLT_MAX; int bi = NN;
    for (int c = t; c < NN; c += 256) { float v = row[c]; if (v > bv) { bv = v; bi = c; } }
    for (int off = 32; off; off >>= 1) {
      float ov = __shfl_down(bv, off); int oi = __shfl_down(bi, off);
      if (ov > bv || (ov == bv && oi < bi)) { bv = ov; bi = oi; }
    }
    if ((t & 63) == 0) { rv[t >> 6] = bv; ri[t >> 6] = bi; }
    __syncthreads();
    if (t == 0) {
      float fv = rv[0]; int fi = ri[0];
      for (int w = 1; w < 4; ++w)
        if (rv[w] > fv || (rv[w] == fv && ri[w] < fi)) { fv = rv[w]; fi = ri[w]; }
      b[fi >> 5] |= 1u << (fi & 31);
      row[fi] = -FLT_MAX;
    }
    __syncthreads();
  }
  if (t < 128) bits[(size_t)i * 128 + t] = b[t];
}

// ---------------------------------------------------------------------------
// 5) A = I - alpha * dots * (bit(i,j)|bit(j,i)), in place over dots.
// ---------------------------------------------------------------------------
__global__ __launch_bounds__(256) void build_A(
    float* __restrict__ A, const unsigned int* __restrict__ bits,
    const float* __restrict__ alpha_p)
{
  int tid = blockIdx.x * 256 + threadIdx.x;
  int i = tid >> 10;
  int j4 = (tid & 1023) << 2;
  float alpha = alpha_p[0];
  float* p = A + (size_t)i * NN + j4;
  float4 d = *(float4*)p;
  unsigned int wrow = bits[(size_t)i * 128 + (j4 >> 5)];
  float dv[4] = {d.x, d.y, d.z, d.w}, o[4];
  #pragma unroll
  for (int u = 0; u < 4; ++u) {
    int j = j4 + u;
    unsigned int m1 = (wrow >> (j & 31)) & 1u;
    unsigned int m2 = (bits[(size_t)j * 128 + (i >> 5)] >> (i & 31)) & 1u;
    float base = (i == j) ? 1.0f : 0.0f;
    o[u] = base - ((m1 | m2) ? alpha * dv[u] : 0.0f);
  }
  *(float4*)p = make_float4(o[0], o[1], o[2], o[3]);
}

// ---------------------------------------------------------------------------
// 6) LU panel (NB=16 cols), partial pivoting. One WG, 1024 threads;
//    a[4][16] = 64 VGPRs -> no spill at the 128-VGPR/wave cap of 16-wave WGs.
// ---------------------------------------------------------------------------
__global__ __launch_bounds__(1024) void lu_panel(
    float* __restrict__ A, int k0, int* __restrict__ piv,
    int* __restrict__ pr_dst, int* __restrict__ pr_src)
{
  const int t = threadIdx.x;
  const int M = NN - k0;
  float a[4][NB];
  __shared__ float bufA[NB], bufB[NB];
  __shared__ float rv[16]; __shared__ int ri[16];
  __shared__ int s_pr;
  __shared__ int piv_s[NB];

  #pragma unroll
  for (int i = 0; i < 4; ++i) {
    int r = t + (i << 10);
    if (r < M) {
      const float* src = A + (size_t)(k0 + r) * NN + k0;
      #pragma unroll
      for (int c4 = 0; c4 < NB; c4 += 4) {
        float4 v = ldg4(src + c4);
        a[i][c4] = v.x; a[i][c4+1] = v.y; a[i][c4+2] = v.z; a[i][c4+3] = v.w;
      }
    }
  }

  #pragma unroll
  for (int j = 0; j < NB; ++j) {
    // pivot search over rows r >= j
    float bv = -1.0f; int br = 1 << 30;
    #pragma unroll
    for (int i = 0; i < 4; ++i) {
      int r = t + (i << 10);
      if (r >= j && r < M) {
        float v = fabsf(a[i][j]);
        if (v > bv || (v == bv && r < br)) { bv = v; br = r; }
      }
    }
    for (int off = 32; off; off >>= 1) {
      float ov = __shfl_down(bv, off); int orr = __shfl_down(br, off);
      if (ov > bv || (ov == bv && orr < br)) { bv = ov; br = orr; }
    }
    if ((t & 63) == 0) { rv[t >> 6] = bv; ri[t >> 6] = br; }
    __syncthreads();
    if (t == 0) {
      float fv = rv[0]; int fr = ri[0];
      for (int w = 1; w < 16; ++w)
        if (rv[w] > fv || (rv[w] == fv && ri[w] < fr)) { fv = rv[w]; fr = ri[w]; }
      s_pr = fr; piv_s[j] = k0 + fr;
    }
    __syncthreads();
    const int pr = s_pr, prT = pr & 1023, prS = pr >> 10;
    // swap rows j <-> pr via LDS (panel cols only)
    if (t == prT) {
      #pragma unroll
      for (int i2 = 0; i2 < 4; ++i2) if (i2 == prS) {
        #pragma unroll
        for (int c = 0; c < NB; ++c) bufB[c] = a[i2][c];
      }
    }
    if (t == j) {
      #pragma unroll
      for (int c = 0; c < NB; ++c) bufA[c] = a[0][c];
    }
    __syncthreads();
    if (t == j) {
      #pragma unroll
      for (int c = 0; c < NB; ++c) a[0][c] = bufB[c];
    }
    if (t == prT) {
      #pragma unroll
      for (int i2 = 0; i2 < 4; ++i2) if (i2 == prS) {
        #pragma unroll
        for (int c = 0; c < NB; ++c) a[i2][c] = bufA[c];
      }
    }
    // scale + rank-1 update (bufB = post-swap pivot row)
    float rp = 1.0f / bufB[j];
    #pragma unroll
    for (int i = 0; i < 4; ++i) {
      int r = t + (i << 10);
      if (r > j && r < M) {
        float mlt = a[i][j] * rp;
        a[i][j] = mlt;
        #pragma unroll
        for (int c = j + 1; c < NB; ++c) a[i][c] -= mlt * bufB[c];
      }
    }
    __syncthreads();
  }

  // writeback
  #pragma unroll
  for (int i = 0; i < 4; ++i) {
    int r = t + (i << 10);
    if (r < M) {
      float* dst = A + (size_t)(k0 + r) * NN + k0;
      #pragma unroll
      for (int c4 = 0; c4 < NB; c4 += 4)
        *(float4*)(dst + c4) = make_float4(a[i][c4], a[i][c4+1], a[i][c4+2], a[i][c4+3]);
    }
  }
  if (t < NB) piv[k0 + t] = piv_s[t];

  // net-permutation simulation on wave 0 (<=32 touched slots for NB=16)
  if (t < 32) {
    int slotrow = (t < NB) ? (k0 + t) : -1;
    int content = slotrow;
    int next_ext = NB;
    for (int j = 0; j < NB; ++j) {
      int p = piv_s[j];
      unsigned long long mask = __ballot(slotrow == p);
      int bslot;
      if (mask) bslot = __ffsll((unsigned long long)mask) - 1;
      else {
        bslot = next_ext;
        if (t == next_ext) { slotrow = p; content = p; }
        next_ext++;
      }
      int srcl = (t == j) ? bslot : ((t == bslot) ? j : t);
      content = __shfl(content, srcl);
    }
    pr_dst[t] = slotrow;   // -1 for unused slots
    pr_src[t] = content;
  }
}

// ---------------------------------------------------------------------------
// 7) apply panel's net row permutation to all columns outside the panel.
// ---------------------------------------------------------------------------
__global__ __launch_bounds__(256) void laswp_pairs(
    float* __restrict__ A, int k0,
    const int* __restrict__ pr_dst, const int* __restrict__ pr_src)
{
  __shared__ int sd[32], ss[32];
  int t = threadIdx.x;
  if (t < 32) { sd[t] = pr_dst[t]; ss[t] = pr_src[t]; }
  __syncthreads();
  int cg = blockIdx.x * 256 + t;
  if (cg >= NN - NB) return;
  int c = (cg < k0) ? cg : cg + NB;
  float tmp[32];
  #pragma unroll
  for (int i = 0; i < 32; ++i)
    tmp[i] = (sd[i] >= 0 && sd[i] != ss[i]) ? A[(size_t)ss[i] * NN + c] : 0.0f;
  #pragma unroll
  for (int i = 0; i < 32; ++i)
    if (sd[i] >= 0 && sd[i] != ss[i]) A[(size_t)sd[i] * NN + c] = tmp[i];
}

// ---------------------------------------------------------------------------
// 8) TRSM: U12 = L11^{-1} * A12 (unit lower 16x16), one column per thread.
// ---------------------------------------------------------------------------
__global__ __launch_bounds__(256) void trsm16(float* __restrict__ A, int k0)
{
  __shared__ float l[16][17];
  int t = threadIdx.x;
  if (t < 256) {
    int i = t >> 4, j = t & 15;
    l[i][j] = A[(size_t)(k0 + i) * NN + k0 + j];
  }
  __syncthreads();
  int c = k0 + NB + blockIdx.x * 256 + t;
  if (c >= NN) return;
  float x[16];
  #pragma unroll
  for (int i = 0; i < 16; ++i) x[i] = A[(size_t)(k0 + i) * NN + c];
  #pragma unroll
  for (int i = 1; i < 16; ++i)
    #pragma unroll
    for (int j = 0; j < i; ++j) x[i] -= l[i][j] * x[j];
  #pragma unroll
  for (int i = 0; i < 16; ++i) A[(size_t)(k0 + i) * NN + c] = x[i];
}

// ---------------------------------------------------------------------------
// 9) generic in-place C -= Aop * Bop  (K multiple of 16). 64x64 tile, KT=16.
// ---------------------------------------------------------------------------
__global__ __launch_bounds__(256) void rank_update(
    float* __restrict__ C, int ldc,
    const float* __restrict__ Aop, int lda,
    const float* __restrict__ Bop, int ldb,
    int Mr, int Nc, int K)
{
  __shared__ float As[16][68], Bs[16][68];
  const int m0 = blockIdx.x * 64, n0 = blockIdx.y * 64;
  const int t = threadIdx.x, tr = t >> 4, tc = t & 15;
  const float4 z4 = make_float4(0.f, 0.f, 0.f, 0.f);
  float acc[4][4] = {};
  for (int kb = 0; kb < K; kb += 16) {
    {
      int m = t >> 2, k4 = (t & 3) << 2;   // 64 rows x 16 k
      float4 v0 = (m0 + m < Mr) ? ldg4(Aop + (size_t)(m0 + m) * lda + kb + k4) : z4;
      As[k4+0][m] = v0.x; As[k4+1][m] = v0.y; As[k4+2][m] = v0.z; As[k4+3][m] = v0.w;
    }
    {
      int kr = t >> 4, n4 = (t & 15) << 2; // 16 k x 64 cols
      bool ok = (n0 + n4 < Nc);
      float4 w0 = ok ? ldg4(Bop + (size_t)(kb + kr) * ldb + n0 + n4) : z4;
      *(float4*)&Bs[kr][n4] = w0;
    }
    __syncthreads();
    #pragma unroll
    for (int kkk = 0; kkk < 16; ++kkk) {
      float a[4], b[4];
      *(float4*)a = *(const float4*)&As[kkk][tr << 2];
      *(float4*)b = *(const float4*)&Bs[kkk][tc << 2];
      #pragma unroll
      for (int r = 0; r < 4; ++r)
        #pragma unroll
        for (int c = 0; c < 4; ++c) acc[r][c] += a[r] * b[c];
    }
    __syncthreads();
  }
  #pragma unroll
  for (int r = 0; r < 4; ++r) {
    int m = m0 + (tr << 2) + r;
    int n = n0 + (tc << 2);
    if (m < Mr && n < Nc) {
      float* cp = C + (size_t)m * ldc + n;
      float4 cv = *(float4*)cp;
      cv.x -= acc[r][0]; cv.y -= acc[r][1]; cv.z -= acc[r][2]; cv.w -= acc[r][3];
      *(float4*)cp = cv;
    }
  }
}

// ---------------------------------------------------------------------------
// 10) invert the 32 diagonal 128x128 blocks of L (unit lower) / U (upper).
// ---------------------------------------------------------------------------
__global__ __launch_bounds__(128) void inv_tri(
    const float* __restrict__ Ag, float* __restrict__ invT, int upper)
{
  __shared__ float xs[128][128];
  const int s = blockIdx.x, t = threadIdx.x;
  const size_t r0 = (size_t)s * SB;
  for (int i = 0; i < 128; ++i) xs[i][t] = 0.0f;
  const float* Tb = Ag + r0 * NN + r0;
  if (!upper) {
    xs[t][t] = 1.0f;
    for (int i = 1; i < 128; ++i) {
      float ssum = 0.f;
      for (int j = 0; j < i; ++j) ssum += Tb[(size_t)i * NN + j] * xs[j][t];
      if (i != t) xs[i][t] = -ssum;
    }
  } else {
    xs[t][t] = 1.0f / Tb[(size_t)t * NN + t];
    for (int i = 126; i >= 0; --i) {
      float ssum = 0.f;
      for (int j = i + 1; j < 128; ++j) ssum += Tb[(size_t)i * NN + j] * xs[j][t];
      if (i != t) xs[i][t] = -ssum / Tb[(size_t)i * NN + i];
    }
  }
  for (int i = 0; i < 128; ++i) invT[(size_t)s * SB * SB + (size_t)i * SB + t] = xs[i][t];
}

// ---------------------------------------------------------------------------
// 11) compose pivot swaps into a gather permutation idxp.
// ---------------------------------------------------------------------------
__global__ __launch_bounds__(1024) void perm_compose(
    const int* __restrict__ piv, int* __restrict__ idxp)
{
  __shared__ int pl[NN];
  const int t = threadIdx.x;
  for (int j = t; j < NN; j += 1024) pl[j] = piv[j];
  __syncthreads();
  int pos[4] = { t, t + 1024, t + 2048, t + 3072 };
  for (int j = NN - 1; j >= 0; --j) {
    int p = pl[j];
    #pragma unroll
    for (int u = 0; u < 4; ++u) {
      int r = t + (u << 10);
      if (j <= r) {
        if (pos[u] == j) pos[u] = p;
        else if (pos[u] == p) pos[u] = j;
      }
    }
  }
  #pragma unroll
  for (int u = 0; u < 4; ++u) idxp[t + (u << 10)] = pos[u];
}

// 12) out[r][:] = xf[idxp[r]][:]
__global__ __launch_bounds__(256) void gather_rows(
    const float* __restrict__ xf, const int* __restrict__ idxp, float* __restrict__ out)
{
  const int r = blockIdx.x, t = threadIdx.x;
  const int src = idxp[r];
  const float4* s = (const float4*)(xf + (size_t)src * DD);
  float4* d = (float4*)(out + (size_t)r * DD);
  for (int c = t; c < DD / 4; c += 256) d[c] = s[c];
}

// ---------------------------------------------------------------------------
// 13) in-place diag block apply: B[r0:r0+128, :] = Minv(128x128) @ same.
// ---------------------------------------------------------------------------
__global__ __launch_bounds__(256) void diag_apply(
    float* __restrict__ B, const float* __restrict__ Minv, int r0)
{
  __shared__ float Bs[128][68];
  const int c0 = blockIdx.x * 64, t = threadIdx.x;
  #pragma unroll
  for (int v = 0; v < 8; ++v) {
    int id = t + v * 256;
    int k = id >> 4, c4 = (id & 15) << 2;
    *(float4*)&Bs[k][c4] = ldg4(B + (size_t)(r0 + k) * DD + c0 + c4);
  }
  __syncthreads();
  const int tr = t >> 4, tc = t & 15;
  float acc[8][4] = {};
  for (int k4 = 0; k4 < 128; k4 += 4) {
    float b0[4], b1[4], b2[4], b3[4];
    *(float4*)b0 = *(const float4*)&Bs[k4+0][tc << 2];
    *(float4*)b1 = *(const float4*)&Bs[k4+1][tc << 2];
    *(float4*)b2 = *(const float4*)&Bs[k4+2][tc << 2];
    *(float4*)b3 = *(const float4*)&Bs[k4+3][tc << 2];
    #pragma unroll
    for (int rr = 0; rr < 8; ++rr) {
      float m[4]; *(float4*)m = ldg4(Minv + (size_t)(tr*8 + rr) * SB + k4);
      #pragma unroll
      for (int c = 0; c < 4; ++c)
        acc[rr][c] += m[0]*b0[c] + m[1]*b1[c] + m[2]*b2[c] + m[3]*b3[c];
    }
  }
  #pragma unroll
  for (int rr = 0; rr < 8; ++rr)
    *(float4*)(B + (size_t)(r0 + tr*8 + rr) * DD + c0 + (tc << 2)) =
        make_float4(acc[rr][0], acc[rr][1], acc[rr][2], acc[rr][3]);
}

// ---------------------------------------------------------------------------
extern "C" void kernel_launch(void* const* d_in, const int* in_sizes, int n_in,
                              void* d_out, int out_size, void* d_ws, size_t ws_size,
                              hipStream_t stream)
{
  const float* xf    = (const float*)d_in[0];
  const float* Wq    = (const float*)d_in[1];
  const float* Wk    = (const float*)d_in[2];
  const float* alpha = (const float*)d_in[3];
  float* out = (float*)d_out;
  char* ws = (char*)d_ws;

  // workspace layout
  float* Amat = (float*)(ws);                          // 64 MB  (dots -> A -> LU)
  float* q    = (float*)(ws + 67108864ull);            // 8 MB
  float* kbuf = (float*)(ws + 75497472ull);            // 8 MB
  float* invL = (float*)(ws + 83886080ull);            // 2 MB
  float* invU = (float*)(ws + 85983232ull);            // 2 MB
  unsigned int* bits = (unsigned int*)(ws + 88080384ull); // 2 MB
  float* q2   = (float*)(ws + 90177536ull);
  float* k2   = (float*)(ws + 90193920ull);
  int* piv    = (int*)(ws + 90210304ull);
  int* idxp   = (int*)(ws + 90226688ull);
  int* prd    = (int*)(ws + 90243072ull);              // 256 panels x 32
  int* prs    = (int*)(ws + 90275840ull);

  proj_gemm<<<dim3(NN/64, DE/64), 256, 0, stream>>>(xf, Wq, Wk, q, kbuf);
  rownorm<<<2 * NN / 4, 256, 0, stream>>>(q, kbuf, q2, k2);
  dots_gemm<<<dim3(NN/64, NN/64), 256, 0, stream>>>(q, kbuf, q2, k2, Amat);
  topk_bits<<<NN, 256, 0, stream>>>(Amat, bits);
  build_A<<<NN * NN / 4 / 256, 256, 0, stream>>>(Amat, bits, alpha);

  // LU with partial pivoting, NB=16 panels
  for (int p = 0; p < NPAN; ++p) {
    int k0 = p * NB;
    lu_panel<<<1, 1024, 0, stream>>>(Amat, k0, piv, prd + p * 32, prs + p * 32);
    laswp_pairs<<<(NN - NB + 255) / 256, 256, 0, stream>>>(Amat, k0, prd + p * 32, prs + p * 32);
    if (k0 + NB < NN) {
      int M2 = NN - k0 - NB;
      trsm16<<<(M2 + 255) / 256, 256, 0, stream>>>(Amat, k0);
      rank_update<<<dim3((M2 + 63) / 64, (M2 + 63) / 64), 256, 0, stream>>>(
          Amat + (size_t)(k0 + NB) * NN + (k0 + NB), NN,
          Amat + (size_t)(k0 + NB) * NN + k0, NN,
          Amat + (size_t)k0 * NN + (k0 + NB), NN,
          M2, M2, NB);
    }
  }

  inv_tri<<<NSB, 128, 0, stream>>>(Amat, invL, 0);
  inv_tri<<<NSB, 128, 0, stream>>>(Amat, invU, 1);
  perm_compose<<<1, 1024, 0, stream>>>(piv, idxp);
  gather_rows<<<NN, 256, 0, stream>>>(xf, idxp, out);

  // forward solve L y = P b  (right-looking, block 128)
  for (int s = 0; s < NSB; ++s) {
    int r0 = s * SB;
    diag_apply<<<DD / 64, 256, 0, stream>>>(out, invL + (size_t)s * SB * SB, r0);
    if (r0 + SB < NN) {
      int M2 = NN - r0 - SB;
      rank_update<<<dim3(M2 / 64, DD / 64), 256, 0, stream>>>(
          out + (size_t)(r0 + SB) * DD, DD,
          Amat + (size_t)(r0 + SB) * NN + r0, NN,
          out + (size_t)r0 * DD, DD,
          M2, DD, SB);
    }
  }
  // backward solve U x = y
  for (int s = NSB - 1; s >= 0; --s) {
    int r0 = s * SB;
    diag_apply<<<DD / 64, 256, 0, stream>>>(out, invU + (size_t)s * SB * SB, r0);
    if (r0 > 0) {
      rank_update<<<dim3(r0 / 64, DD / 64), 256, 0, stream>>>(
          out, DD,
          Amat + r0, NN,
          out + (size_t)r0 * DD, DD,
          r0, DD, SB);
    }
  }
}